// Round 1
// baseline (3353.751 us; speedup 1.0000x reference)
//
#include <hip/hip_runtime.h>

// Problem constants (LoraConv: B=32,E=5,CIN=COUT=256,K=3,H=W=56,R=4, scaling=16/4=4)
#define BB    32
#define EE    5
#define CINC  256
#define COUTC 256
#define KF    3
#define HH    56
#define WW    56
#define RKD   12          // R*K
#define KKC   2304        // CIN*K*K
#define SCAL  4.0f
#define DELTA_PER_E (COUTC * KKC)   // 589824 floats per expert

// ---------------------------------------------------------------------------
// Kernel 1: top-1 expert per sample (first-max semantics like jnp.argmax)
// ---------------------------------------------------------------------------
__global__ void lora_expert_kernel(const float* __restrict__ scores,
                                   int* __restrict__ experts) {
    int b = threadIdx.x;
    if (b < BB) {
        const float* s = scores + b * EE;
        int best = 0;
        float bv = s[0];
        #pragma unroll
        for (int j = 1; j < EE; ++j) {
            float v = s[j];
            if (v > bv) { bv = v; best = j; }   // strict > keeps first max
        }
        experts[b] = best;
    }
}

// ---------------------------------------------------------------------------
// Kernel 2: per-expert delta weights, flat layout == weight layout
//   delta[e][f] = SCAL * sum_r lora_B[e, f/768, r] * lora_A[e, r, f%768]
// One block per (o_idx, e) row; coalesced A reads.
// ---------------------------------------------------------------------------
__global__ __launch_bounds__(256) void lora_delta_kernel(
    const float* __restrict__ lora_A,   // [E,12,768]
    const float* __restrict__ lora_B,   // [E,768,12]
    float* __restrict__ delta)          // [E,589824]
{
    const int o = blockIdx.x;   // 0..767
    const int e = blockIdx.y;   // 0..4

    __shared__ float Brow[RKD];
    if (threadIdx.x < RKD)
        Brow[threadIdx.x] = lora_B[((size_t)e * 768 + o) * RKD + threadIdx.x];
    __syncthreads();

    const float* Ae   = lora_A + (size_t)e * RKD * 768;
    float*       drow = delta + (size_t)e * DELTA_PER_E + (size_t)o * 768;

    for (int i = threadIdx.x; i < 768; i += 256) {
        float acc = 0.f;
        #pragma unroll
        for (int r = 0; r < RKD; ++r)
            acc += Brow[r] * Ae[r * 768 + i];
        drow[i] = acc * SCAL;
    }
}

// ---------------------------------------------------------------------------
// Kernel 3: direct conv. Block = (output row y, 32-channel co tile, sample b).
// 256 threads: thread = (o = tid>>3 in 0..31, pg = tid&7), owns 7 pixels.
// K-loop over input channels in chunks of 8, staging x halo + fused W+delta
// in LDS.
// ---------------------------------------------------------------------------
__global__ __launch_bounds__(256) void lora_conv_kernel(
    const float* __restrict__ x,        // [B,CIN,H,W]
    const float* __restrict__ weight,   // [COUT,CIN,3,3]
    const float* __restrict__ delta,    // [E,COUT,CIN,3,3] flat
    const int*   __restrict__ experts,  // [B]
    float* __restrict__ out)            // [B,COUT,H,W]
{
    const int y      = blockIdx.x;   // 0..55
    const int ct     = blockIdx.y;   // 0..7
    const int b      = blockIdx.z;   // 0..31
    const int e      = experts[b];
    const int cobase = ct * 32;

    __shared__ float xs[8][3][58];    // [c_chunk][row k1][col -1..56]
    __shared__ float wsm[32][72];     // [co][c*9 + k1*3 + k2]

    const int tid = threadIdx.x;
    const int o   = tid >> 3;        // 0..31
    const int pg  = tid & 7;         // 0..7  -> pixels pg*7 .. pg*7+6

    float acc[7];
    #pragma unroll
    for (int j = 0; j < 7; ++j) acc[j] = 0.f;

    const float* xb    = x + (size_t)b * CINC * HH * WW;
    const float* wbase = weight + (size_t)cobase * KKC;
    const float* dbase = delta + (size_t)e * DELTA_PER_E + (size_t)cobase * KKC;

    for (int cb = 0; cb < CINC; cb += 8) {
        __syncthreads();   // previous iteration's LDS reads done

        // stage x halo tile: 8 channels x 3 rows x 58 cols = 1392 floats
        for (int t = tid; t < 1392; t += 256) {
            int c   = t / 174;
            int rm  = t % 174;
            int rr  = rm / 58;
            int cc  = rm % 58;
            int row = y + rr - 1;
            int col = cc - 1;
            float v = 0.f;
            if ((unsigned)row < HH && (unsigned)col < WW)
                v = xb[(size_t)(cb + c) * (HH * WW) + row * WW + col];
            xs[c][rr][cc] = v;
        }
        // stage fused weights: 32 co x 72 = 2304 floats
        for (int t = tid; t < 2304; t += 256) {
            int co = t / 72;
            int j  = t % 72;   // c*9 + kk
            size_t gidx = (size_t)co * KKC + (size_t)cb * 9 + j;
            wsm[co][j] = wbase[gidx] + dbase[gidx];
        }
        __syncthreads();

        #pragma unroll
        for (int c = 0; c < 8; ++c) {
            #pragma unroll
            for (int k1 = 0; k1 < 3; ++k1) {
                float xr[9];
                #pragma unroll
                for (int j = 0; j < 9; ++j)
                    xr[j] = xs[c][k1][pg * 7 + j];
                #pragma unroll
                for (int k2 = 0; k2 < 3; ++k2) {
                    float w = wsm[o][c * 9 + k1 * 3 + k2];
                    #pragma unroll
                    for (int j = 0; j < 7; ++j)
                        acc[j] += w * xr[k2 + j];
                }
            }
        }
    }

    float* ob = out + (((size_t)b * COUTC + cobase + o) * HH + y) * WW + pg * 7;
    #pragma unroll
    for (int j = 0; j < 7; ++j) ob[j] = acc[j];
}

// ---------------------------------------------------------------------------
extern "C" void kernel_launch(void* const* d_in, const int* in_sizes, int n_in,
                              void* d_out, int out_size, void* d_ws, size_t ws_size,
                              hipStream_t stream) {
    const float* x      = (const float*)d_in[0];
    const float* scores = (const float*)d_in[1];
    const float* weight = (const float*)d_in[2];
    const float* lora_A = (const float*)d_in[3];
    const float* lora_B = (const float*)d_in[4];
    float* out = (float*)d_out;

    // workspace layout: [0,128) experts (32 ints), then per-expert delta (fp32)
    int*   experts = (int*)d_ws;
    float* delta   = (float*)((char*)d_ws + 128);

    lora_expert_kernel<<<1, 64, 0, stream>>>(scores, experts);
    lora_delta_kernel<<<dim3(768, EE), 256, 0, stream>>>(lora_A, lora_B, delta);
    lora_conv_kernel<<<dim3(56, 8, BB), 256, 0, stream>>>(x, weight, delta, experts, out);
}

// Round 2
// 411.825 us; speedup vs baseline: 8.1436x; 8.1436x over previous
//
#include <hip/hip_runtime.h>
#include <hip/hip_bf16.h>

// LoraConv: B=32,E=5,CIN=COUT=256,K=3,H=W=56,R=4, scaling=4
#define BB    32
#define EE    5
#define CINC  256
#define COUTC 256
#define HH    56
#define WW    56
#define KKC   2304
#define SCAL  4.0f

typedef __attribute__((ext_vector_type(8))) short short8;
typedef __attribute__((ext_vector_type(4))) float f32x4;

// xpad: [B][58][58][256] bf16, zero halo.  Wf: [E][9][256 o][256 ci] bf16.
#define XP_PER_B   (58 * 58 * 256)
#define WF_PER_ET  (256 * 256)

__device__ __forceinline__ void gload_lds16(const void* g, void* l) {
    __builtin_amdgcn_global_load_lds(
        (const __attribute__((address_space(1))) unsigned int*)g,
        (__attribute__((address_space(3))) unsigned int*)l, 16, 0, 0);
}

// ---------------------------------------------------------------------------
// Kernel 1: top-1 expert per sample (first-max, like jnp.argmax)
// ---------------------------------------------------------------------------
__global__ void lora_expert_kernel(const float* __restrict__ scores,
                                   int* __restrict__ experts) {
    int b = threadIdx.x;
    if (b < BB) {
        const float* s = scores + b * EE;
        int best = 0; float bv = s[0];
        #pragma unroll
        for (int j = 1; j < EE; ++j) { float v = s[j]; if (v > bv) { bv = v; best = j; } }
        experts[b] = best;
    }
}

// ---------------------------------------------------------------------------
// Kernel 2: fused weights Wf[e][tap][co][ci] = bf16(W[co][ci][k1][k2] + SCAL*BA)
//   Delta flat index co*2304+ci*9+tap == o768*768+i768 of einsum('eor,eri').
//   o768 = co*3 + (ci*9+tap)/768 ; i768 = (ci*9+tap)%768
// Block = (co, e); thread = ci.
// ---------------------------------------------------------------------------
__global__ __launch_bounds__(256) void lora_prep_kernel(
    const float* __restrict__ weight,   // [256,256,3,3]
    const float* __restrict__ lora_A,   // [E,12,768]
    const float* __restrict__ lora_B,   // [E,768,12]
    __hip_bfloat16* __restrict__ Wf)    // [E,9,256,256]
{
    const int co = blockIdx.x;
    const int e  = blockIdx.y;
    const int ci = threadIdx.x;

    __shared__ float As[12 * 768];
    __shared__ float Bs[3][12];
    for (int i = threadIdx.x; i < 12 * 768; i += 256)
        As[i] = lora_A[e * 12 * 768 + i];
    if (threadIdx.x < 36)
        Bs[threadIdx.x / 12][threadIdx.x % 12] =
            lora_B[((size_t)e * 768 + co * 3 + threadIdx.x / 12) * 12 + threadIdx.x % 12];
    __syncthreads();

    const float* wrow = weight + (size_t)co * KKC + ci * 9;
    #pragma unroll
    for (int tap = 0; tap < 9; ++tap) {
        int idx  = ci * 9 + tap;
        int q    = idx / 768;
        int i768 = idx - q * 768;
        float acc = 0.f;
        #pragma unroll
        for (int r = 0; r < 12; ++r)
            acc += Bs[q][r] * As[r * 768 + i768];
        float v = wrow[tap] + SCAL * acc;
        Wf[((size_t)(e * 9 + tap) * 256 + co) * 256 + ci] = __float2bfloat16(v);
    }
}

// ---------------------------------------------------------------------------
// Kernel 3: transpose+pad x -> xpad[b][r'][c'][ci] bf16 (r'=row+1,c'=col+1, halo=0)
// Block = (r' 0..57, b). LDS tile transpose per 64-ci chunk.
// ---------------------------------------------------------------------------
__global__ __launch_bounds__(256) void lora_xpose_kernel(
    const float* __restrict__ x,        // [B,256,56,56]
    __hip_bfloat16* __restrict__ xpad)
{
    const int rp = blockIdx.x;   // 0..57
    const int b  = blockIdx.y;
    const int tid = threadIdx.x;
    __hip_bfloat16* xpb = xpad + (size_t)b * XP_PER_B;

    if (rp == 0 || rp == 57) {  // zero whole halo row: 58*256 bf16 = 29696 B
        uint4* rowp = (uint4*)(xpb + (size_t)rp * 58 * 256);
        uint4 z; z.x = z.y = z.z = z.w = 0;
        for (int i = tid; i < 1856; i += 256) rowp[i] = z;
        return;
    }
    const int row = rp - 1;
    {   // zero column halos c'=0 and c'=57 (256 bf16 = 512 B each)
        uint4 z; z.x = z.y = z.z = z.w = 0;
        if (tid < 32)       ((uint4*)(xpb + ((size_t)rp * 58 + 0)  * 256))[tid]      = z;
        else if (tid < 64)  ((uint4*)(xpb + ((size_t)rp * 58 + 57) * 256))[tid - 32] = z;
    }

    __shared__ float xt[64][57];
    const float* xb = x + (size_t)b * CINC * HH * WW;
    for (int cb = 0; cb < 256; cb += 64) {
        __syncthreads();
        #pragma unroll
        for (int it = 0; it < 14; ++it) {        // 64 ci x 56 cols, coalesced read
            int t = it * 256 + tid;
            int i = t / 56, c = t % 56;
            xt[i][c] = xb[(size_t)(cb + i) * (HH * WW) + row * WW + c];
        }
        __syncthreads();
        #pragma unroll
        for (int it = 0; it < 14; ++it) {        // write [c'][ci] contiguous
            int t = it * 256 + tid;
            int j = t & 63, c = t >> 6;          // j=ci_local, c=col
            xpb[((size_t)rp * 58 + (c + 1)) * 256 + cb + j] = __float2bfloat16(xt[j][c]);
        }
    }
}

// ---------------------------------------------------------------------------
// Kernel 4: implicit-GEMM conv via MFMA bf16 16x16x32.
// Block: 128 co x 112 pos (2 rows), K = 72 chunks (tap-major, 32 ci each).
// 16B LDS granules XOR-swizzled: phys(row,g) = row*4 + (g ^ ((row>>1)&3)).
// ---------------------------------------------------------------------------
__global__ __launch_bounds__(256) void lora_conv_mfma_kernel(
    const __hip_bfloat16* __restrict__ xpad,
    const __hip_bfloat16* __restrict__ Wf,
    const int* __restrict__ experts,
    float* __restrict__ out)
{
    const int y0  = blockIdx.x * 2;     // output row pair
    const int co0 = blockIdx.y * 128;   // co tile
    const int b   = blockIdx.z;
    const int e   = experts[b];

    const int tid  = threadIdx.x;
    const int wave = tid >> 6;
    const int lane = tid & 63;
    const int ln15 = lane & 15;
    const int quad = lane >> 4;
    const int wm   = wave * 32;         // wave's m-base within 128

    __shared__ short8 Wlds[512];        // 128 rows x 4 granules (8 KB)
    __shared__ short8 Xlds[448];        // 112 rows x 4 granules (7 KB)

    const short* WfS = (const short*)Wf;
    const short* xpS = (const short*)xpad;

    // ---- precomputed staging descriptors (per thread) ----
    // W: granule G = i*256+tid, row ol=G>>2, logical g=(G&3)^((ol>>1)&3)
    int wOff[2];
    #pragma unroll
    for (int i = 0; i < 2; ++i) {
        int G  = i * 256 + tid;
        int ol = G >> 2;
        int g  = (G & 3) ^ ((ol >> 1) & 3);
        wOff[i] = (e * 9) * WF_PER_ET + (co0 + ol) * 256 + g * 8;  // + t*65536 + ci0
    }
    // X: granule G (only G<448), row pos=G>>2
    int xOff[2]; bool xAct[2];
    #pragma unroll
    for (int i = 0; i < 2; ++i) {
        int G = i * 256 + tid;
        xAct[i] = (G < 448);
        int pos = (G < 448) ? (G >> 2) : 0;
        int g   = (G & 3) ^ ((pos >> 1) & 3);
        int r   = pos >= 56 ? 1 : 0;
        int c   = pos - r * 56;
        xOff[i] = b * XP_PER_B + ((y0 + r) * 58 + c) * 256 + g * 8;  // + (k1*58+k2)*256 + ci0
    }
    // fragment read physical granules (constant across chunks)
    int aphys[2], bphys[7];
    #pragma unroll
    for (int tm = 0; tm < 2; ++tm) {
        int row = wm + tm * 16 + ln15;
        aphys[tm] = (row << 2) + (quad ^ ((row >> 1) & 3));
    }
    #pragma unroll
    for (int tn = 0; tn < 7; ++tn) {
        int pos = tn * 16 + ln15;
        bphys[tn] = (pos << 2) + (quad ^ ((pos >> 1) & 3));
    }

    f32x4 acc[2][7];
    #pragma unroll
    for (int tm = 0; tm < 2; ++tm)
        #pragma unroll
        for (int tn = 0; tn < 7; ++tn)
            acc[tm][tn] = (f32x4){0.f, 0.f, 0.f, 0.f};

    for (int chunk = 0; chunk < 72; ++chunk) {
        const int t   = chunk >> 3;          // tap 0..8
        const int ci0 = (chunk & 7) << 5;    // 0..224
        const int k1  = t / 3, k2 = t - k1 * 3;
        const int wAdd = t * WF_PER_ET + ci0;
        const int xAdd = (k1 * 58 + k2) * 256 + ci0;

        __syncthreads();   // prior chunk's LDS reads complete
        #pragma unroll
        for (int i = 0; i < 2; ++i) {
            int G = i * 256 + tid;
            gload_lds16(WfS + wOff[i] + wAdd, (char*)Wlds + (size_t)G * 16);
        }
        #pragma unroll
        for (int i = 0; i < 2; ++i) {
            if (xAct[i]) {
                int G = i * 256 + tid;
                gload_lds16(xpS + xOff[i] + xAdd, (char*)Xlds + (size_t)G * 16);
            }
        }
        __syncthreads();   // loads landed (barrier drains vmcnt)

        short8 afr[2], bfr[7];
        #pragma unroll
        for (int tm = 0; tm < 2; ++tm) afr[tm] = Wlds[aphys[tm]];
        #pragma unroll
        for (int tn = 0; tn < 7; ++tn) bfr[tn] = Xlds[bphys[tn]];
        #pragma unroll
        for (int tm = 0; tm < 2; ++tm)
            #pragma unroll
            for (int tn = 0; tn < 7; ++tn)
                acc[tm][tn] = __builtin_amdgcn_mfma_f32_16x16x32_bf16(
                    afr[tm], bfr[tn], acc[tm][tn], 0, 0, 0);
    }

    // epilogue: D row = wm + tm*16 + quad*4 + reg, col = tn*16 + ln15
    #pragma unroll
    for (int tm = 0; tm < 2; ++tm) {
        #pragma unroll
        for (int tn = 0; tn < 7; ++tn) {
            int n = tn * 16 + ln15;
            int r = n >= 56 ? 1 : 0;
            int c = n - r * 56;
            #pragma unroll
            for (int reg = 0; reg < 4; ++reg) {
                int m = wm + tm * 16 + quad * 4 + reg;
                out[(((size_t)b * COUTC + co0 + m) * HH + (y0 + r)) * WW + c] =
                    acc[tm][tn][reg];
            }
        }
    }
}

// ---------------------------------------------------------------------------
extern "C" void kernel_launch(void* const* d_in, const int* in_sizes, int n_in,
                              void* d_out, int out_size, void* d_ws, size_t ws_size,
                              hipStream_t stream) {
    const float* x      = (const float*)d_in[0];
    const float* scores = (const float*)d_in[1];
    const float* weight = (const float*)d_in[2];
    const float* lora_A = (const float*)d_in[3];
    const float* lora_B = (const float*)d_in[4];
    float* out = (float*)d_out;

    // workspace: experts (128B) | Wf bf16 (5.9MB) | xpad bf16 (55.1MB)
    char* ws = (char*)d_ws;
    int* experts = (int*)ws;
    __hip_bfloat16* Wf   = (__hip_bfloat16*)(ws + 256);
    __hip_bfloat16* xpad = (__hip_bfloat16*)(ws + 256 + (size_t)EE * 9 * WF_PER_ET * 2);

    lora_expert_kernel<<<1, 64, 0, stream>>>(scores, experts);
    lora_prep_kernel<<<dim3(256, EE), 256, 0, stream>>>(weight, lora_A, lora_B, Wf);
    lora_xpose_kernel<<<dim3(58, BB), 256, 0, stream>>>(x, xpad);
    lora_conv_mfma_kernel<<<dim3(28, 2, BB), 256, 0, stream>>>(xpad, Wf, experts, out);
}

// Round 3
// 374.237 us; speedup vs baseline: 8.9616x; 1.1004x over previous
//
#include <hip/hip_runtime.h>
#include <hip/hip_bf16.h>

// LoraConv: B=32,E=5,CIN=COUT=256,K=3,H=W=56,R=4, scaling=4
#define BB    32
#define EE    5
#define HH    56
#define WW    56
#define KKC   2304
#define SCAL  4.0f

typedef __attribute__((ext_vector_type(8))) short short8;
typedef __attribute__((ext_vector_type(4))) float f32x4;

// Wf2:   [E][9 tap][8 cic][256 co][32 ci] bf16
// xpad2: [B][8 cic][58 row][58 col][32 ci] bf16, zero halo
#define WF2_PER_E  (9 * 8 * 256 * 32)     // 589824
#define XP2_PER_BC (58 * 58 * 32)         // 107648 per (b,cic)

__device__ __forceinline__ void gload_lds16(const void* g, void* l) {
    __builtin_amdgcn_global_load_lds(
        (const __attribute__((address_space(1))) unsigned int*)g,
        (__attribute__((address_space(3))) unsigned int*)l, 16, 0, 0);
}

__device__ __forceinline__ unsigned short f2bf(float f) {   // RNE, finite inputs
    unsigned int u = __float_as_uint(f);
    return (unsigned short)((u + 0x7FFFu + ((u >> 16) & 1u)) >> 16);
}

// ---------------------------------------------------------------------------
// Kernel 1: fused weights -> Wf2[e][tap][cic][co][ci32]
//   delta flat idx co*2304+ci*9+tap == o768*768+i768 of einsum('eor,eri')
// ---------------------------------------------------------------------------
__global__ __launch_bounds__(256) void lora_prep_kernel(
    const float* __restrict__ weight,   // [256,256,3,3]
    const float* __restrict__ lora_A,   // [E,12,768]
    const float* __restrict__ lora_B,   // [E,768,12]
    unsigned short* __restrict__ Wf2)
{
    const int co = blockIdx.x;
    const int e  = blockIdx.y;
    const int ci = threadIdx.x;

    __shared__ float As[12 * 768];
    __shared__ float Bs[3][12];
    for (int i = threadIdx.x; i < 12 * 768; i += 256)
        As[i] = lora_A[e * 12 * 768 + i];
    if (threadIdx.x < 36)
        Bs[threadIdx.x / 12][threadIdx.x % 12] =
            lora_B[((size_t)e * 768 + co * 3 + threadIdx.x / 12) * 12 + threadIdx.x % 12];
    __syncthreads();

    const float* wrow = weight + (size_t)co * KKC + ci * 9;
    const int cic = ci >> 5, ci32 = ci & 31;
    #pragma unroll
    for (int tap = 0; tap < 9; ++tap) {
        int idx  = ci * 9 + tap;
        int q    = idx / 768;
        int i768 = idx - q * 768;
        float acc = 0.f;
        #pragma unroll
        for (int r = 0; r < 12; ++r)
            acc += Bs[q][r] * As[r * 768 + i768];
        float v = wrow[tap] + SCAL * acc;
        Wf2[((size_t)((e * 9 + tap) * 8 + cic)) * 8192 + co * 32 + ci32] = f2bf(v);
    }
}

// ---------------------------------------------------------------------------
// Kernel 2: x[B,256,56,56] fp32 -> xpad2 bf16 (register-only transpose)
// Block = (rp 0..57, b).
// ---------------------------------------------------------------------------
__global__ __launch_bounds__(256) void lora_xpose_kernel(
    const float* __restrict__ x,
    unsigned short* __restrict__ xpad2)
{
    const int rp = blockIdx.x;
    const int b  = blockIdx.y;
    const int tid = threadIdx.x;
    unsigned short* xp = xpad2 + (size_t)b * 8 * XP2_PER_BC;
    const uint4 z4 = {0u, 0u, 0u, 0u};

    if (rp == 0 || rp == 57) {          // full halo row for all 8 cic planes
        for (int t = tid; t < 1856; t += 256) {
            int cic = t / 232, q = t % 232;
            ((uint4*)(xp + ((size_t)cic * 3364 + rp * 58) * 32))[q] = z4;
        }
        return;
    }
    if (tid < 64) {                      // column halos cp=0, cp=57
        int cic = tid >> 3, which = (tid >> 2) & 1, q = tid & 3;
        ((uint4*)(xp + ((size_t)cic * 3364 + rp * 58 + (which ? 57 : 0)) * 32))[q] = z4;
    }

    const int row = rp - 1;
    const float* xb = x + (size_t)b * 256 * 3136 + row * 56;
    #pragma unroll
    for (int it = 0; it < 14; ++it) {    // items: cic(8) x col(56) x g8(8)
        int t   = it * 256 + tid;
        int g8  = t & 7;
        int c   = (t >> 3) % 56;
        int cic = t / 448;
        int ch  = cic * 32 + g8 * 4;
        float v0 = xb[(size_t)(ch + 0) * 3136 + c];
        float v1 = xb[(size_t)(ch + 1) * 3136 + c];
        float v2 = xb[(size_t)(ch + 2) * 3136 + c];
        float v3 = xb[(size_t)(ch + 3) * 3136 + c];
        unsigned int lo = (unsigned int)f2bf(v0) | ((unsigned int)f2bf(v1) << 16);
        unsigned int hi = (unsigned int)f2bf(v2) | ((unsigned int)f2bf(v3) << 16);
        uint2 pk; pk.x = lo; pk.y = hi;
        *(uint2*)(xp + ((size_t)cic * 3364 + rp * 58 + c + 1) * 32 + g8 * 4) = pk;
    }
}

// ---------------------------------------------------------------------------
// Kernel 3: conv. Block = 128 co x 224 pos (4 rows). ci-chunk outer (LDS,
// double-buffered, 1 barrier/chunk), tap inner (9x reuse), W global->VGPR
// with one-tap-ahead prefetch. 252 MFMA per barrier per wave.
// ---------------------------------------------------------------------------
__global__ __launch_bounds__(256) void lora_conv_mfma_kernel(
    const unsigned short* __restrict__ xpad2,
    const unsigned short* __restrict__ Wf2,
    const float* __restrict__ scores,
    float* __restrict__ out)
{
    const int y0   = blockIdx.x * 4;     // output rows y0..y0+3
    const int co0  = blockIdx.y * 128;
    const int b    = blockIdx.z;
    const int tid  = threadIdx.x;
    const int wave = tid >> 6;
    const int lane = tid & 63;
    const int ln15 = lane & 15;
    const int quad = lane >> 4;
    const int wm2  = (wave & 1) * 64;    // co sub-tile
    const int wn2  = (wave >> 1) * 112;  // pos sub-tile

    __shared__ short8 Xlds[2][1392];     // 2 x (6 rows x 58 cols x 4 granules)
    __shared__ int sExp;

    if (tid == 0) {
        const float* s = scores + b * EE;
        int best = 0; float bv = s[0];
        #pragma unroll
        for (int j = 1; j < EE; ++j) { float v = s[j]; if (v > bv) { bv = v; best = j; } }
        sExp = best;
    }

    const unsigned short* xsrc0 = xpad2 + (size_t)b * 8 * XP2_PER_BC + y0 * 58 * 32;

    // stage ci-chunk `cic` into buffer `buf` (22272 B contiguous)
    auto stage = [&](int cic, int buf) {
        const unsigned short* src = xsrc0 + (size_t)cic * XP2_PER_BC;
        char* dst = (char*)&Xlds[buf][0];
        #pragma unroll
        for (int i = 0; i < 5; ++i) {
            int G = i * 256 + tid;
            gload_lds16(src + (size_t)G * 8, dst + (size_t)G * 16);
        }
        if (tid < 112) {
            int G = 1280 + tid;
            gload_lds16(src + (size_t)G * 8, dst + (size_t)G * 16);
        }
    };

    stage(0, 0);
    __syncthreads();
    const int e = sExp;

    // W fragment base: row = co0+wm2+ln15 (+tm*16), k-offset quad*8 (+cic*32)
    const unsigned short* Wb =
        Wf2 + (size_t)e * WF2_PER_E + (co0 + wm2 + ln15) * 32 + quad * 8;
    // strides: tm -> 16*32=512, tap -> 8*8192=65536, cic -> 8192

    // B-fragment granule base per tn (at k1=k2=0)
    int pg[7];
    #pragma unroll
    for (int tn = 0; tn < 7; ++tn) {
        int pos = wn2 + tn * 16 + ln15;
        int r = pos / 56, c = pos % 56;
        pg[tn] = r * 232 + c * 4 + quad;
    }

    f32x4 acc[4][7];
    #pragma unroll
    for (int tm = 0; tm < 4; ++tm)
        #pragma unroll
        for (int tn = 0; tn < 7; ++tn)
            acc[tm][tn] = (f32x4){0.f, 0.f, 0.f, 0.f};

    short8 Acur[4], Anext[4];

    for (int cic = 0; cic < 8; ++cic) {
        const unsigned short* Wc = Wb + cic * 8192;
        #pragma unroll
        for (int tm = 0; tm < 4; ++tm)
            Acur[tm] = *(const short8*)(Wc + tm * 512);       // tap 0

        const short8* Xb = &Xlds[cic & 1][0];
        #pragma unroll
        for (int tap = 0; tap < 9; ++tap) {
            if (tap == 1 && cic < 7) stage(cic + 1, (cic & 1) ^ 1);
            if (tap < 8) {
                #pragma unroll
                for (int tm = 0; tm < 4; ++tm)
                    Anext[tm] = *(const short8*)(Wc + (tap + 1) * 65536 + tm * 512);
            }
            const int k1 = tap / 3, k2 = tap % 3;
            #pragma unroll
            for (int tn = 0; tn < 7; ++tn) {
                short8 bfr = Xb[pg[tn] + k1 * 232 + k2 * 4];
                #pragma unroll
                for (int tm = 0; tm < 4; ++tm)
                    acc[tm][tn] = __builtin_amdgcn_mfma_f32_16x16x32_bf16(
                        Acur[tm], bfr, acc[tm][tn], 0, 0, 0);
            }
            #pragma unroll
            for (int tm = 0; tm < 4; ++tm) Acur[tm] = Anext[tm];
        }
        if (cic < 7) __syncthreads();   // staging landed + reads of old buf done
    }

    // epilogue: D row m = quad*4+reg (+tm*16), col n = ln15 (+tn*16)
    #pragma unroll
    for (int tm = 0; tm < 4; ++tm) {
        #pragma unroll
        for (int tn = 0; tn < 7; ++tn) {
            int n = wn2 + tn * 16 + ln15;
            int r = n / 56, c = n % 56;
            #pragma unroll
            for (int reg = 0; reg < 4; ++reg) {
                int m = co0 + wm2 + tm * 16 + quad * 4 + reg;
                out[(((size_t)b * 256 + m) * HH + y0 + r) * WW + c] = acc[tm][tn][reg];
            }
        }
    }
}

// ---------------------------------------------------------------------------
extern "C" void kernel_launch(void* const* d_in, const int* in_sizes, int n_in,
                              void* d_out, int out_size, void* d_ws, size_t ws_size,
                              hipStream_t stream) {
    const float* x      = (const float*)d_in[0];
    const float* scores = (const float*)d_in[1];
    const float* weight = (const float*)d_in[2];
    const float* lora_A = (const float*)d_in[3];
    const float* lora_B = (const float*)d_in[4];
    float* out = (float*)d_out;

    // workspace: Wf2 bf16 (5.9MB) | xpad2 bf16 (55.1MB)
    char* ws = (char*)d_ws;
    unsigned short* Wf2   = (unsigned short*)(ws + 256);
    unsigned short* xpad2 = (unsigned short*)(ws + 256 + (size_t)EE * WF2_PER_E * 2);

    lora_prep_kernel<<<dim3(256, EE), 256, 0, stream>>>(weight, lora_A, lora_B, Wf2);
    lora_xpose_kernel<<<dim3(58, BB), 256, 0, stream>>>(x, xpad2);
    lora_conv_mfma_kernel<<<dim3(14, 2, BB), 256, 0, stream>>>(xpad2, Wf2, scores, out);
}

// Round 4
// 317.785 us; speedup vs baseline: 10.5535x; 1.1776x over previous
//
#include <hip/hip_runtime.h>
#include <hip/hip_bf16.h>

// LoraConv: B=32,E=5,CIN=COUT=256,K=3,H=W=56,R=4, scaling=4
#define BB    32
#define EE    5
#define HH    56
#define WW    56
#define KKC   2304
#define SCAL  4.0f

typedef __attribute__((ext_vector_type(8))) short short8;
typedef __attribute__((ext_vector_type(4))) float f32x4;

// Wf2:   [E][9 tap][8 cic][256 co][32 ci] bf16
// xpad2: [B][8 cic][58 row][58 col][32 ci] bf16, zero halo.
//        Within each col's 64B group, 16B granule q stored at q ^ ((col>>1)&3).
#define WF2_PER_E  (9 * 8 * 256 * 32)     // 589824
#define XP2_PER_BC (58 * 58 * 32)         // 107648 per (b,cic)

__device__ __forceinline__ void gload_lds16(const void* g, void* l) {
    __builtin_amdgcn_global_load_lds(
        (const __attribute__((address_space(1))) unsigned int*)g,
        (__attribute__((address_space(3))) unsigned int*)l, 16, 0, 0);
}

__device__ __forceinline__ unsigned short f2bf(float f) {   // RNE, finite inputs
    unsigned int u = __float_as_uint(f);
    return (unsigned short)((u + 0x7FFFu + ((u >> 16) & 1u)) >> 16);
}

// ---------------------------------------------------------------------------
// Kernel 1: fused weights -> Wf2[e][tap][cic][co][ci32]  (no swizzle: W goes
// global->VGPR in the conv kernel, never through LDS)
// ---------------------------------------------------------------------------
__global__ __launch_bounds__(256) void lora_prep_kernel(
    const float* __restrict__ weight,   // [256,256,3,3]
    const float* __restrict__ lora_A,   // [E,12,768]
    const float* __restrict__ lora_B,   // [E,768,12]
    unsigned short* __restrict__ Wf2)
{
    const int co = blockIdx.x;
    const int e  = blockIdx.y;
    const int ci = threadIdx.x;

    __shared__ float As[12 * 768];
    __shared__ float Bs[3][12];
    for (int i = threadIdx.x; i < 12 * 768; i += 256)
        As[i] = lora_A[e * 12 * 768 + i];
    if (threadIdx.x < 36)
        Bs[threadIdx.x / 12][threadIdx.x % 12] =
            lora_B[((size_t)e * 768 + co * 3 + threadIdx.x / 12) * 12 + threadIdx.x % 12];
    __syncthreads();

    const float* wrow = weight + (size_t)co * KKC + ci * 9;
    const int cic = ci >> 5, ci32 = ci & 31;
    #pragma unroll
    for (int tap = 0; tap < 9; ++tap) {
        int idx  = ci * 9 + tap;
        int q    = idx / 768;
        int i768 = idx - q * 768;
        float acc = 0.f;
        #pragma unroll
        for (int r = 0; r < 12; ++r)
            acc += Bs[q][r] * As[r * 768 + i768];
        float v = wrow[tap] + SCAL * acc;
        Wf2[((size_t)((e * 9 + tap) * 8 + cic)) * 8192 + co * 32 + ci32] = f2bf(v);
    }
}

// ---------------------------------------------------------------------------
// Kernel 2: x[B,256,56,56] fp32 -> xpad2 bf16, coalesced via LDS tile,
// swizzled 16B granule writes. Block = (rp 0..57, b).
// ---------------------------------------------------------------------------
__global__ __launch_bounds__(256) void lora_xpose_kernel(
    const float* __restrict__ x,
    unsigned short* __restrict__ xpad2)
{
    const int rp  = blockIdx.x;
    const int b   = blockIdx.y;
    const int tid = threadIdx.x;
    unsigned short* xp = xpad2 + (size_t)b * 8 * XP2_PER_BC;
    const uint4 z4 = {0u, 0u, 0u, 0u};

    if (rp == 0 || rp == 57) {          // full halo row for all 8 cic planes
        for (int t = tid; t < 1856; t += 256) {
            int cic = t / 232, q = t % 232;
            ((uint4*)(xp + ((size_t)cic * 3364 + rp * 58) * 32))[q] = z4;
        }
        return;
    }
    if (tid < 64) {                      // column halos cp=0, cp=57
        int cic = tid >> 3, which = (tid >> 2) & 1, q = tid & 3;
        ((uint4*)(xp + ((size_t)cic * 3364 + rp * 58 + (which ? 57 : 0)) * 32))[q] = z4;
    }

    const int row = rp - 1;
    const float* xb = x + (size_t)b * 256 * 3136 + row * 56;
    __shared__ float xt[32][60];

    for (int cic = 0; cic < 8; ++cic) {
        __syncthreads();
        #pragma unroll
        for (int it = 0; it < 7; ++it) {     // 32 ch x 56 cols, coalesced fp32
            int t = it * 256 + tid;
            int i = t / 56, c = t % 56;
            xt[i][c] = xb[(size_t)(cic * 32 + i) * 3136 + c];
        }
        __syncthreads();
        if (tid < 224) {                     // c = tid>>2, logical quad = tid&3
            int c  = tid >> 2, gq = tid & 3;
            int cp = c + 1;
            int gphys = gq ^ ((cp >> 1) & 3);
            unsigned int w[4];
            #pragma unroll
            for (int j = 0; j < 4; ++j) {
                unsigned short lo = f2bf(xt[gq * 8 + 2 * j + 0][c]);
                unsigned short hi = f2bf(xt[gq * 8 + 2 * j + 1][c]);
                w[j] = (unsigned int)lo | ((unsigned int)hi << 16);
            }
            uint4 pk; pk.x = w[0]; pk.y = w[1]; pk.z = w[2]; pk.w = w[3];
            *(uint4*)(xp + ((size_t)cic * 3364 + rp * 58 + cp) * 32 + gphys * 8) = pk;
        }
    }
}

// ---------------------------------------------------------------------------
// Kernel 3: conv. Block = 128 co x 224 pos (4 rows). ci-chunk outer (LDS X,
// double-buffered, 1 barrier/chunk), tap inner (9x reuse), W global->VGPR
// with one-tap-ahead prefetch. 252 MFMA per barrier per wave.
// Swizzled LDS: granule(row,col,q) at (row*58+col)*4 + (q ^ ((col>>1)&3)).
// ---------------------------------------------------------------------------
__global__ __launch_bounds__(256, 2) void lora_conv_mfma_kernel(
    const unsigned short* __restrict__ xpad2,
    const unsigned short* __restrict__ Wf2,
    const float* __restrict__ scores,
    float* __restrict__ out)
{
    const int y0   = blockIdx.x * 4;     // output rows y0..y0+3
    const int co0  = blockIdx.y * 128;
    const int b    = blockIdx.z;
    const int tid  = threadIdx.x;
    const int wave = tid >> 6;
    const int lane = tid & 63;
    const int ln15 = lane & 15;
    const int quad = lane >> 4;
    const int wm2  = (wave & 1) * 64;    // co sub-tile
    const int wn2  = (wave >> 1) * 112;  // pos sub-tile

    __shared__ short8 Xlds[2][1392];     // 2 x (6 rows x 58 cols x 4 granules)
    __shared__ int sExp;

    if (tid == 0) {
        const float* s = scores + b * EE;
        int best = 0; float bv = s[0];
        #pragma unroll
        for (int j = 1; j < EE; ++j) { float v = s[j]; if (v > bv) { bv = v; best = j; } }
        sExp = best;
    }

    const unsigned short* xsrc0 = xpad2 + (size_t)b * 8 * XP2_PER_BC + y0 * 58 * 32;

    // stage ci-chunk `cic` into buffer `buf` (22272 B contiguous)
    auto stage = [&](int cic, int buf) {
        const unsigned short* src = xsrc0 + (size_t)cic * XP2_PER_BC;
        char* dst = (char*)&Xlds[buf][0];
        #pragma unroll
        for (int i = 0; i < 5; ++i) {
            int G = i * 256 + tid;
            gload_lds16(src + (size_t)G * 8, dst + (size_t)G * 16);
        }
        if (tid < 112) {
            int G = 1280 + tid;
            gload_lds16(src + (size_t)G * 8, dst + (size_t)G * 16);
        }
    };

    stage(0, 0);
    __syncthreads();
    const int e = sExp;

    // W fragment base: row = co0+wm2+ln15 (+tm*16), k-offset quad*8 (+cic*32)
    const unsigned short* Wb =
        Wf2 + (size_t)e * WF2_PER_E + (co0 + wm2 + ln15) * 32 + quad * 8;
    // strides (shorts): tm -> 512, tap -> 65536, cic -> 8192

    // B-fragment byte offsets per (tn, k2); k1 adds 3712 via ds offset imm
    int pgk[7][3];
    #pragma unroll
    for (int tn = 0; tn < 7; ++tn) {
        int pos = wn2 + tn * 16 + ln15;
        int r = pos / 56, c = pos % 56;
        #pragma unroll
        for (int k2 = 0; k2 < 3; ++k2) {
            int cc = c + k2;
            int g  = quad ^ ((cc >> 1) & 3);
            pgk[tn][k2] = (r * 232 + cc * 4 + g) * 16;
        }
    }

    f32x4 acc[4][7];
    #pragma unroll
    for (int tm = 0; tm < 4; ++tm)
        #pragma unroll
        for (int tn = 0; tn < 7; ++tn)
            acc[tm][tn] = (f32x4){0.f, 0.f, 0.f, 0.f};

    short8 Acur[4], Anext[4];

    for (int cic = 0; cic < 8; ++cic) {
        const unsigned short* Wc = Wb + cic * 8192;
        #pragma unroll
        for (int tm = 0; tm < 4; ++tm)
            Acur[tm] = *(const short8*)(Wc + tm * 512);       // tap 0

        const char* Xb = (const char*)&Xlds[cic & 1][0];
        #pragma unroll
        for (int tap = 0; tap < 9; ++tap) {
            if (tap == 1 && cic < 7) stage(cic + 1, (cic & 1) ^ 1);
            if (tap < 8) {
                #pragma unroll
                for (int tm = 0; tm < 4; ++tm)
                    Anext[tm] = *(const short8*)(Wc + (tap + 1) * 65536 + tm * 512);
            }
            const int k1 = tap / 3, k2 = tap % 3;
            #pragma unroll
            for (int tn = 0; tn < 7; ++tn) {
                short8 bfr = *(const short8*)(Xb + pgk[tn][k2] + k1 * 3712);
                #pragma unroll
                for (int tm = 0; tm < 4; ++tm)
                    acc[tm][tn] = __builtin_amdgcn_mfma_f32_16x16x32_bf16(
                        Acur[tm], bfr, acc[tm][tn], 0, 0, 0);
            }
            #pragma unroll
            for (int tm = 0; tm < 4; ++tm) Acur[tm] = Anext[tm];
        }
        if (cic < 7) __syncthreads();   // staging landed + old-buf reads done
    }

    // epilogue: D row m = quad*4+reg (+tm*16), col n = ln15 (+tn*16)
    #pragma unroll
    for (int tm = 0; tm < 4; ++tm) {
        #pragma unroll
        for (int tn = 0; tn < 7; ++tn) {
            int n = wn2 + tn * 16 + ln15;
            int r = n / 56, c = n % 56;
            #pragma unroll
            for (int reg = 0; reg < 4; ++reg) {
                int m = co0 + wm2 + tm * 16 + quad * 4 + reg;
                out[(((size_t)b * 256 + m) * HH + y0 + r) * WW + c] = acc[tm][tn][reg];
            }
        }
    }
}

// ---------------------------------------------------------------------------
extern "C" void kernel_launch(void* const* d_in, const int* in_sizes, int n_in,
                              void* d_out, int out_size, void* d_ws, size_t ws_size,
                              hipStream_t stream) {
    const float* x      = (const float*)d_in[0];
    const float* scores = (const float*)d_in[1];
    const float* weight = (const float*)d_in[2];
    const float* lora_A = (const float*)d_in[3];
    const float* lora_B = (const float*)d_in[4];
    float* out = (float*)d_out;

    // workspace: Wf2 bf16 (5.9MB) | xpad2 bf16 (55.1MB)
    char* ws = (char*)d_ws;
    unsigned short* Wf2   = (unsigned short*)(ws + 256);
    unsigned short* xpad2 = (unsigned short*)(ws + 256 + (size_t)EE * WF2_PER_E * 2);

    lora_prep_kernel<<<dim3(256, EE), 256, 0, stream>>>(weight, lora_A, lora_B, Wf2);
    lora_xpose_kernel<<<dim3(58, BB), 256, 0, stream>>>(x, xpad2);
    lora_conv_mfma_kernel<<<dim3(14, 2, BB), 256, 0, stream>>>(xpad2, Wf2, scores, out);
}